// Round 18
// baseline (447.354 us; speedup 1.0000x reference)
//
#include <hip/hip_runtime.h>

// PointNet 2-stage fused pipeline, MI355X gfx950.  Round 18.
// k_stage2 v10: B STREAMED FROM L2 TO REGISTERS (W3t/W4t = 262KB, L2-hot).
// Bs LDS pipeline deleted -> barriers 36 -> 5 per block; LDS 37.3KB.
// bf loads are transient per-phase (#pragma unroll 1 prevents hoisting; NOT
// the failed persistent-weights family: ~8 bf VGPR live at a time).
// pf4 row-major [64][264], pf5 col-major [256][72] (r17-validated).
// P1-split, mmv1, mmv2, sort: unchanged validated round-17 code.

#define NPTS 524288
#define NVOX 32768

typedef _Float16 f16;
typedef _Float16 f16x4 __attribute__((ext_vector_type(4)));
typedef _Float16 f16x8 __attribute__((ext_vector_type(8)));
typedef float f32x4 __attribute__((ext_vector_type(4)));

#define GLDS16(g, l)                                                          \
  __builtin_amdgcn_global_load_lds(                                           \
      (const __attribute__((address_space(1))) unsigned int*)(const void*)(g),\
      (__attribute__((address_space(3))) unsigned int*)(void*)(l), 16, 0, 0)

// ---------- idx normalization: auto-detect int32 vs int64 storage ----------
__global__ void k_fixidx(const int* __restrict__ raw, int* __restrict__ out) {
  bool is64 = true;
#pragma unroll
  for (int k = 0; k < 32; ++k)
    if (raw[2 * k + 1] != 0) is64 = false;   // int64 high words all 0 (vals < 32768)
  int stride = gridDim.x * blockDim.x;
  for (int i = blockIdx.x * blockDim.x + threadIdx.x; i < NPTS; i += stride)
    out[i] = is64 ? raw[2 * i] : raw[i];
}

// ---------- counting sort ----------
__global__ void k_hist(const int* __restrict__ idx, int* __restrict__ counts) {
  int stride = gridDim.x * blockDim.x;
  for (int i = blockIdx.x * blockDim.x + threadIdx.x; i < NPTS; i += stride)
    atomicAdd(&counts[idx[i]], 1);
}

__global__ void k_scan(const int* __restrict__ counts, int* __restrict__ offsets) {
  __shared__ int part[1024];
  __shared__ int sums[32];
  int t = threadIdx.x;
  int loc[32];
  int s = 0;
#pragma unroll
  for (int j = 0; j < 32; ++j) { loc[j] = counts[t * 32 + j]; s += loc[j]; }
  part[t] = s;
  __syncthreads();
  if (t < 32) {
    int run = 0;
    for (int j = 0; j < 32; ++j) { int tmp = part[t * 32 + j]; part[t * 32 + j] = run; run += tmp; }
    sums[t] = run;
  }
  __syncthreads();
  if (t == 0) {
    int run = 0;
    for (int i = 0; i < 32; ++i) { int tmp = sums[i]; sums[i] = run; run += tmp; }
  }
  __syncthreads();
  int b = part[t] + sums[t >> 5];
#pragma unroll
  for (int j = 0; j < 32; ++j) { offsets[t * 32 + j] = b; b += loc[j]; }
  if (t == 1023) offsets[NVOX] = b;
}

__global__ void k_scat(const int* __restrict__ idx, const int* __restrict__ offsets,
                       int* __restrict__ cursor, int* __restrict__ sp, int* __restrict__ sv) {
  int stride = gridDim.x * blockDim.x;
  for (int i = blockIdx.x * blockDim.x + threadIdx.x; i < NPTS; i += stride) {
    int v = idx[i];
    int pos = offsets[v] + atomicAdd(&cursor[v], 1);
    sp[pos] = i;
    sv[pos] = v;
  }
}

// ---------- standalone mlp1: pf1[s] = f16(relu(x[sp[s]] @ W1 + b1)) --------
__global__ void k_mlp1(const float* __restrict__ x, const int* __restrict__ sp,
                       const float* __restrict__ W1, const float* __restrict__ b1,
                       f16* __restrict__ pf1) {
  __shared__ float w[384];
  __shared__ float bb[64];
  int t = threadIdx.x;
  if (t < 384) w[t] = W1[t];
  if (t < 64) bb[t] = b1[t];
  __syncthreads();
  int stride = gridDim.x * blockDim.x;
  for (int s = blockIdx.x * blockDim.x + t; s < NPTS; s += stride) {
    int p = sp[s];
    const float* src = x + (size_t)p * 6;
    float x0 = src[0], x1 = src[1], x2 = src[2];
    float x3 = src[3], x4 = src[4], x5 = src[5];
    f16* dst = pf1 + (size_t)s * 64;
#pragma unroll
    for (int j0 = 0; j0 < 64; j0 += 8) {
      f16x8 o;
#pragma unroll
      for (int u = 0; u < 8; ++u) {
        int j = j0 + u;
        float a = bb[j];
        a += x0 * w[j];       a += x1 * w[64 + j];
        a += x2 * w[128 + j]; a += x3 * w[192 + j];
        a += x4 * w[256 + j]; a += x5 * w[320 + j];
        o[u] = (f16)fmaxf(a, 0.f);
      }
      *(f16x8*)(dst + j0) = o;
    }
  }
}

// ---------- weight transpose+cast: Wt[n][k] = (f16)W[k][n] ----------
__global__ void k_wcast(const float* __restrict__ W, f16* __restrict__ Wt, int K, int N) {
  int g = blockIdx.x * blockDim.x + threadIdx.x;
  if (g >= K * N) return;
  int k = g / N, n = g % N;
  Wt[n * K + k] = (f16)W[g];
}

__global__ void k_castf(const float* __restrict__ in, f16* __restrict__ out, int n) {
  int stride = gridDim.x * blockDim.x;
  for (int i = blockIdx.x * blockDim.x + threadIdx.x; i < n; i += stride)
    out[i] = (f16)in[i];
}

// ---------- generic f16 MFMA GEMM (validated round-4/6 core) ---------------
template <int K, int N, int MODEA, bool SCATTER, bool OUTF32, bool WRITEO, bool WTILE>
__global__ __launch_bounds__(256, 3) void k_gemm(
    const f16* __restrict__ A,
    const int* __restrict__ sv, const int* __restrict__ sp,
    const int* __restrict__ offs,
    const float* __restrict__ x, const float* __restrict__ W1, const float* __restrict__ b1,
    const f16* __restrict__ Bt,   // [N][K] pre-transposed
    const float* __restrict__ bias,
    f16* __restrict__ Of16, float* __restrict__ Of32, int row0) {
  constexpr int NT = N / 128;
  __shared__ __align__(16) char smem[32768];
  __shared__ float xs[MODEA == 2 ? 768 : 1];
  __shared__ int svp[MODEA == 2 ? 128 : 1];
  __shared__ int svx[SCATTER ? 128 : 1];
  f16* As = (f16*)smem;            // [128][64] per K-tile, 16B chunks XOR-swizzled
  f16* Bs = As + 128 * 64;

  int nwg = gridDim.x;             // all grids are multiples of 8
  int bid = blockIdx.x;
  int q = nwg >> 3;
  int swz = (bid & 7) * q + (bid >> 3);   // bijective XCD swizzle
  int tm = swz / NT, tn = swz % NT;
  int t = threadIdx.x;

  if (MODEA == 2) { if (t < 128) svp[t] = sp[row0 + tm * 128 + t]; }
  if (SCATTER) { if (t < 128) svx[t] = sv[row0 + tm * 128 + t]; }
  if (MODEA == 2) __syncthreads();

  int l = t & 63, w = t >> 6;
  int wm = w >> 1, wn = w & 1;
  int lrow = l & 15, lk = l >> 4;
  f32x4 acc[4][4] = {};

  constexpr int KT = K / 64;
#pragma unroll
  for (int kt = 0; kt < KT; ++kt) {
    int k0 = kt * 64;
#pragma unroll
    for (int i = 0; i < 4; ++i) {
      int n = i * 32 + (t >> 3);
      int clog = (t & 7) ^ (n & 7);
      GLDS16(Bt + (size_t)(tn * 128 + n) * K + k0 + clog * 8, Bs + i * 2048 + t * 8);
    }
    if constexpr (MODEA == 2) {
      for (int g = t; g < 768; g += 256) xs[g] = x[(size_t)svp[g / 6] * 6 + (g % 6)];
      __syncthreads();
      int j = t & 63;
      float wv[6];
#pragma unroll
      for (int i = 0; i < 6; ++i) wv[i] = W1[i * 64 + j];
      float bb = b1[j];
      int rb = (t >> 6) * 32;
#pragma unroll
      for (int rr = 0; rr < 32; ++rr) {
        int row = rb + rr;
        float a = bb;
#pragma unroll
        for (int i = 0; i < 6; ++i) a += xs[row * 6 + i] * wv[i];
        As[row * 64 + (((j >> 3) ^ (row & 7)) << 3) + (j & 7)] = (f16)fmaxf(a, 0.f);
      }
    } else {
#pragma unroll
      for (int i = 0; i < 4; ++i) {
        int row = i * 32 + (t >> 3);
        int clog = (t & 7) ^ (row & 7);
        GLDS16(A + (size_t)(tm * 128 + row) * K + k0 + clog * 8, As + i * 2048 + t * 8);
      }
    }
    __syncthreads();
#pragma unroll
    for (int ks = 0; ks < 2; ++ks) {
      f16x8 af[4], bf[4];
#pragma unroll
      for (int m = 0; m < 4; ++m) {
        int row = wm * 64 + m * 16 + lrow;
        int cp = (ks * 4 + lk) ^ (row & 7);
        af[m] = *(const f16x8*)(As + row * 64 + cp * 8);
      }
#pragma unroll
      for (int n = 0; n < 4; ++n) {
        int col = wn * 64 + n * 16 + lrow;
        int cp = (ks * 4 + lk) ^ (col & 7);
        bf[n] = *(const f16x8*)(Bs + col * 64 + cp * 8);
      }
#pragma unroll
      for (int m = 0; m < 4; ++m)
#pragma unroll
        for (int n = 0; n < 4; ++n)
          acc[m][n] = __builtin_amdgcn_mfma_f32_16x16x32_f16(af[m], bf[n], acc[m][n], 0, 0, 0);
    }
    __syncthreads();
  }

  if constexpr (WRITEO) {
#pragma unroll
    for (int m = 0; m < 4; ++m)
#pragma unroll
      for (int n = 0; n < 4; ++n)
#pragma unroll
        for (int j = 0; j < 4; ++j) {
          int row = wm * 64 + m * 16 + lk * 4 + j;       // C/D: row=(l>>4)*4+j
          int gc  = tn * 128 + wn * 64 + n * 16 + lrow;  // col=l&15
          float val = fmaxf(acc[m][n][j] + bias[gc], 0.f);
          if constexpr (OUTF32) Of32[(size_t)(tm * 128 + row) * N + gc] = val;
          else                  Of16[(size_t)(tm * 128 + row) * N + gc] = (f16)val;
        }
  }

  if constexpr (SCATTER) {
    f16* tile = (f16*)smem;   // [128][128] f16 (32KB, reuses As/Bs)
#pragma unroll
    for (int m = 0; m < 4; ++m)
#pragma unroll
      for (int n = 0; n < 4; ++n)
#pragma unroll
        for (int j = 0; j < 4; ++j) {
          int row = wm * 64 + m * 16 + lk * 4 + j;
          int col = wn * 64 + n * 16 + lrow;
          tile[row * 128 + col] =
              (f16)fmaxf(acc[m][n][j] + bias[tn * 128 + col], 0.f);
        }
    __syncthreads();
    if constexpr (WTILE) {
      // coalesced pf2 write from tile (values bit-identical to tile entries)
      f16* dst = Of16 + (size_t)(row0 + tm * 128) * 128;
#pragma unroll
      for (int i = 0; i < 8; ++i) {
        int g = i * 256 + t;
        *(f16x8*)(dst + g * 8) = *(const f16x8*)(tile + g * 8);
      }
    }
    int c = t & 127, h = t >> 7;    // 2 segments x 64 rows
    int r0l = h * 64;
    int gc = tn * 128 + c;
    int grow0 = row0 + tm * 128 + r0l;
    float run = 0.f;
    int curv = svx[r0l];
    for (int r = r0l; r < r0l + 64; ++r) {
      int v = svx[r];
      if (v != curv) {
        bool inter = (offs[curv] >= grow0) && (offs[curv + 1] <= grow0 + 64);
        if (inter) Of32[(size_t)curv * N + gc] = run;
        else atomicMax((int*)&Of32[(size_t)curv * N + gc], __float_as_int(run));
        curv = v; run = 0.f;
      }
      run = fmaxf(run, (float)tile[r * 128 + c]);
    }
    bool inter = (offs[curv] >= grow0) && (offs[curv + 1] <= grow0 + 64);
    if (inter) Of32[(size_t)curv * N + gc] = run;
    else atomicMax((int*)&Of32[(size_t)curv * N + gc], __float_as_int(run));
  }
}

// ---------- fused stage 2 v10: B streamed L2->regs, 5 barriers/block -------
// 64 rows/block, 512 thr / 8 waves; wave w owns cols [w*32, w*32+32).
// A staged full-K once via GLDS (chunk-XOR [64][32ch]); bf loaded per phase
// directly from W3t/W4t (L2-hot, transient regs, unroll 1). No Bs LDS.
// pf4 row-major [64][264]; pf5 col-major [256][72]. LDS 37.3KB.
__global__ __launch_bounds__(512, 2) void k_stage2(
    const f16* __restrict__ pf2, const f16* __restrict__ occ1,
    const int* __restrict__ sv, const int* __restrict__ offs,
    const f16* __restrict__ W3t, const float* __restrict__ b3,
    const f16* __restrict__ W4t, const float* __restrict__ b4,
    float* __restrict__ vox2f, int row0) {
  __shared__ __align__(16) f16 PF[64 * 288];   // 36.9KB: A-full / pf4 / pf5(cm)
  __shared__ int svx[64];

  int nwg = gridDim.x;
  int bid = blockIdx.x;
  int q = nwg >> 3;
  int bm = (bid & 7) * q + (bid >> 3);   // bijective XCD swizzle
  int t = threadIdx.x;
  int l = t & 63, w = t >> 6;
  int lrow = l & 15, lk = l >> 4;

  if (t < 64) svx[t] = sv[row0 + bm * 64 + t];
  __syncthreads();

  // ---- stage A full-K [64 rows][32 chunks], chunk-XOR ----
  f16* Afull = PF;   // linear [64][256] with low-3-bit chunk XOR
#pragma unroll
  for (int ii = 0; ii < 4; ++ii) {
    int g = ii * 512 + t;
    int row = g >> 5, cs = g & 31;
    int cl = (cs & 24) | ((cs ^ row) & 7);   // inverse-swizzled source chunk
    const f16* src;
    if (cl < 16) src = occ1 + (size_t)svx[row] * 128 + cl * 8;
    else         src = pf2 + (size_t)(bm * 64 + row) * 128 + (cl - 16) * 8;
    GLDS16(src, Afull + g * 8);
  }
  __syncthreads();   // [B1] A ready (drains glds)

  f32x4 acc[4][2] = {};
  // per-lane W base: this lane's two columns
  const f16* w3c0 = W3t + (size_t)(w * 32 + lrow) * 256 + lk * 8;
  const f16* w3c1 = w3c0 + 16 * 256;
  const f16* w4c0 = W4t + (size_t)(w * 32 + lrow) * 256 + lk * 8;
  const f16* w4c1 = w4c0 + 16 * 256;

  // ---------------- mm3: 8 phases of K=32, no barriers ----------------------
#pragma unroll 1
  for (int p = 0; p < 8; ++p) {
    f16x8 bf0 = *(const f16x8*)(w3c0 + p * 32);
    f16x8 bf1 = *(const f16x8*)(w3c1 + p * 32);
    __builtin_amdgcn_s_setprio(1);
    f16x8 af[4];
#pragma unroll
    for (int m = 0; m < 4; ++m) {
      int row = m * 16 + lrow;
      int ab = p * 4 + lk;
      int slot = (ab & 24) | ((ab ^ row) & 7);
      af[m] = *(const f16x8*)(Afull + row * 256 + slot * 8);
    }
#pragma unroll
    for (int m = 0; m < 4; ++m) {
      acc[m][0] = __builtin_amdgcn_mfma_f32_16x16x32_f16(af[m], bf0, acc[m][0], 0, 0, 0);
      acc[m][1] = __builtin_amdgcn_mfma_f32_16x16x32_f16(af[m], bf1, acc[m][1], 0, 0, 0);
    }
    __builtin_amdgcn_s_setprio(0);
  }
  __syncthreads();   // [B2] all A reads done -> PF reusable

  // ---- pf4 into PF region, row-major [64][264] ----------------------------
  f16* pf4 = PF;
#pragma unroll
  for (int m = 0; m < 4; ++m)
#pragma unroll
    for (int n = 0; n < 2; ++n)
#pragma unroll
      for (int j = 0; j < 4; ++j) {
        int row  = m * 16 + lk * 4 + j;      // C/D: row=(l>>4)*4+j, col=l&15
        int colg = w * 32 + n * 16 + lrow;
        pf4[row * 264 + colg] = (f16)fmaxf(acc[m][n][j] + b3[colg], 0.f);
      }
  __syncthreads();   // [B3] pf4 ready

#pragma unroll
  for (int m = 0; m < 4; ++m)
#pragma unroll
    for (int n = 0; n < 2; ++n)
      acc[m][n] = (f32x4){0.f, 0.f, 0.f, 0.f};

  // ---------------- mm4: 8 phases of K=32, no barriers ----------------------
#pragma unroll 1
  for (int p = 0; p < 8; ++p) {
    f16x8 bf0 = *(const f16x8*)(w4c0 + p * 32);
    f16x8 bf1 = *(const f16x8*)(w4c1 + p * 32);
    __builtin_amdgcn_s_setprio(1);
    f16x8 af[4];
#pragma unroll
    for (int m = 0; m < 4; ++m) {
      int row = m * 16 + lrow;
      int chunk = p * 4 + lk;                 // 0..31
      af[m] = *(const f16x8*)(pf4 + row * 264 + chunk * 8);
    }
#pragma unroll
    for (int m = 0; m < 4; ++m) {
      acc[m][0] = __builtin_amdgcn_mfma_f32_16x16x32_f16(af[m], bf0, acc[m][0], 0, 0, 0);
      acc[m][1] = __builtin_amdgcn_mfma_f32_16x16x32_f16(af[m], bf1, acc[m][1], 0, 0, 0);
    }
    __builtin_amdgcn_s_setprio(0);
  }
  __syncthreads();   // [B4] all pf4 reads done -> PF reusable

  // ---- pf5 COLUMN-MAJOR [256 cols][72]: b64 stores ------------------------
  f16* pf5 = PF;
#pragma unroll
  for (int m = 0; m < 4; ++m)
#pragma unroll
    for (int n = 0; n < 2; ++n) {
      int colg = w * 32 + n * 16 + lrow;
      int rowb = m * 16 + lk * 4;
      float bv = b4[colg];
      f16x4 v;
#pragma unroll
      for (int j = 0; j < 4; ++j) v[j] = (f16)fmaxf(acc[m][n][j] + bv, 0.f);
      *(f16x4*)(pf5 + colg * 72 + rowb) = v;
    }
  __syncthreads();   // [B5] pf5 ready

  // ---------------- scatter-max scan: vectorized col-major reads -----------
  {
    int c = t & 255, seg = t >> 8;   // 256 cols x 2 segs of 32 rows
    int r0l = seg * 32;
    int grow0 = row0 + bm * 64 + r0l;
    const f16* colp = pf5 + c * 72;
    float run = 0.f;
    int curv = svx[r0l];
#pragma unroll
    for (int rb = 0; rb < 32; rb += 8) {
      f16x8 vv = *(const f16x8*)(colp + r0l + rb);
#pragma unroll
      for (int u = 0; u < 8; ++u) {
        int r = r0l + rb + u;
        int v = svx[r];
        if (v != curv) {
          bool inter = (offs[curv] >= grow0) && (offs[curv + 1] <= grow0 + 32);
          if (inter) vox2f[(size_t)curv * 256 + c] = run;
          else atomicMax((int*)&vox2f[(size_t)curv * 256 + c], __float_as_int(run));
          curv = v; run = 0.f;
        }
        run = fmaxf(run, (float)vv[u]);
      }
    }
    bool inter = (offs[curv] >= grow0) && (offs[curv + 1] <= grow0 + 32);
    if (inter) vox2f[(size_t)curv * 256 + c] = run;
    else atomicMax((int*)&vox2f[(size_t)curv * 256 + c], __float_as_int(run));
  }
}

extern "C" void kernel_launch(void* const* d_in, const int* in_sizes, int n_in,
                              void* d_out, int out_size, void* d_ws, size_t ws_size,
                              hipStream_t stream) {
  const float* x   = (const float*)d_in[0];
  const int*  idxr = (const int*)d_in[1];
  const float* W1  = (const float*)d_in[3];
  const float* b1  = (const float*)d_in[4];
  const float* W2  = (const float*)d_in[5];
  const float* b2  = (const float*)d_in[6];
  const float* Wv1 = (const float*)d_in[7];
  const float* bv1 = (const float*)d_in[8];
  const float* W3  = (const float*)d_in[9];
  const float* b3  = (const float*)d_in[10];
  const float* W4  = (const float*)d_in[11];
  const float* b4  = (const float*)d_in[12];
  const float* Wv2 = (const float*)d_in[13];
  const float* bv2 = (const float*)d_in[14];
  float* out = (float*)d_out;

  char* ws = (char*)d_ws;
  size_t off = 0;
  auto alloc = [&](size_t bytes) {
    void* p = ws + off;
    off = (off + bytes + 255) & ~(size_t)255;
    return p;
  };
  int* idx     = (int*)alloc((size_t)NPTS * 4);
  int* counts  = (int*)alloc((size_t)NVOX * 4);
  int* cursor  = (int*)alloc((size_t)NVOX * 4);
  int* offs    = (int*)alloc((size_t)(NVOX + 1) * 4);
  int* sp      = (int*)alloc((size_t)NPTS * 4);
  int* sv      = (int*)alloc((size_t)NPTS * 4);
  f16* W2t     = (f16*)alloc(64 * 128 * 2);
  f16* Wv1t    = (f16*)alloc(128 * 128 * 2);
  f16* W3t     = (f16*)alloc(256 * 256 * 2);
  f16* W4t     = (f16*)alloc(256 * 256 * 2);
  f16* Wv2t    = (f16*)alloc(256 * 256 * 2);
  float* vox1f = (float*)alloc((size_t)NVOX * 128 * 4);
  f16* vox1h   = (f16*)alloc((size_t)NVOX * 128 * 2);
  f16* occ1    = (f16*)alloc((size_t)NVOX * 128 * 2);
  float* vox2f = (float*)alloc((size_t)NVOX * 256 * 4);

  // adaptive: pf2 full? + pf1 (split mlp1)?
  size_t rem = (ws_size > off) ? ws_size - off : 0;
  bool PF2FULL = rem >= (size_t)NPTS * 256 + 4096;
  int CH = 65536;
  f16* pf2   = (f16*)alloc(PF2FULL ? (size_t)NPTS * 256 : (size_t)CH * 256);
  f16* vox2h = pf2;   // overlay: pf2 dead once stage2 done
  size_t rem2 = (ws_size > off) ? ws_size - off : 0;
  bool MLP1SPLIT = PF2FULL && rem2 >= (size_t)NPTS * 128 + 4096;
  f16* pf1 = MLP1SPLIT ? (f16*)alloc((size_t)NPTS * 128) : nullptr;

  hipMemsetAsync(counts, 0, (size_t)NVOX * 4, stream);
  hipMemsetAsync(cursor, 0, (size_t)NVOX * 4, stream);
  hipMemsetAsync(vox1f, 0, (size_t)NVOX * 128 * 4, stream);
  hipMemsetAsync(vox2f, 0, (size_t)NVOX * 256 * 4, stream);

  k_fixidx<<<2048, 256, 0, stream>>>(idxr, idx);
  k_wcast<<<(64 * 128 + 255) / 256, 256, 0, stream>>>(W2, W2t, 64, 128);
  k_wcast<<<(128 * 128 + 255) / 256, 256, 0, stream>>>(Wv1, Wv1t, 128, 128);
  k_wcast<<<(256 * 256 + 255) / 256, 256, 0, stream>>>(W3, W3t, 256, 256);
  k_wcast<<<(256 * 256 + 255) / 256, 256, 0, stream>>>(W4, W4t, 256, 256);
  k_wcast<<<(256 * 256 + 255) / 256, 256, 0, stream>>>(Wv2, Wv2t, 256, 256);
  k_hist<<<2048, 256, 0, stream>>>(idx, counts);
  k_scan<<<1, 1024, 0, stream>>>(counts, offs);
  k_scat<<<2048, 256, 0, stream>>>(idx, offs, cursor, sp, sv);

  // P1: mlp1 (split or fused) + mm2 + segment-max -> vox1f (+ pf2)
  if (MLP1SPLIT) {
    k_mlp1<<<2048, 256, 0, stream>>>(x, sp, W1, b1, pf1);
    k_gemm<64, 128, 0, true, false, false, true><<<NPTS / 128, 256, 0, stream>>>(
        pf1, sv, sp, offs, x, W1, b1, W2t, b2, pf2, vox1f, 0);
  } else if (PF2FULL) {
    k_gemm<64, 128, 2, true, false, false, true><<<NPTS / 128, 256, 0, stream>>>(
        nullptr, sv, sp, offs, x, W1, b1, W2t, b2, pf2, vox1f, 0);
  } else {
    k_gemm<64, 128, 2, true, false, false, false><<<NPTS / 128, 256, 0, stream>>>(
        nullptr, sv, sp, offs, x, W1, b1, W2t, b2, nullptr, vox1f, 0);
  }
  k_castf<<<2048, 256, 0, stream>>>(vox1f, vox1h, NVOX * 128);
  // mmv1: occ1 = relu(vox1 @ Wv1 + bv1)
  k_gemm<128, 128, 0, false, false, true, false><<<NVOX / 128, 256, 0, stream>>>(
      vox1h, nullptr, nullptr, nullptr, nullptr, nullptr, nullptr,
      Wv1t, bv1, occ1, nullptr, 0);

  // stage 2: fused mm3+mm4+scatter (B streamed from L2)
  if (PF2FULL) {
    k_stage2<<<NPTS / 64, 512, 0, stream>>>(
        pf2, occ1, sv, offs, W3t, b3, W4t, b4, vox2f, 0);
  } else {
    for (int c = 0; c < NPTS / CH; ++c) {
      int row0 = c * CH;
      k_gemm<64, 128, 2, false, false, true, false><<<CH / 128, 256, 0, stream>>>(
          nullptr, nullptr, sp, nullptr, x, W1, b1, W2t, b2, pf2, nullptr, row0);
      k_stage2<<<CH / 64, 512, 0, stream>>>(
          pf2, occ1, sv, offs, W3t, b3, W4t, b4, vox2f, row0);
    }
  }

  k_castf<<<2048, 256, 0, stream>>>(vox2f, vox2h, NVOX * 256);
  // mmv2: out = relu(vox2 @ Wv2 + bv2), f32 output via MFMA
  k_gemm<256, 256, 0, false, true, true, false><<<(NVOX / 128) * 2, 256, 0, stream>>>(
      vox2h, nullptr, nullptr, nullptr, nullptr, nullptr, nullptr,
      Wv2t, bv2, nullptr, out, 0);
}

// Round 19
// 380.676 us; speedup vs baseline: 1.1752x; 1.1752x over previous
//
#include <hip/hip_runtime.h>

// PointNet 2-stage fused pipeline, MI355X gfx950.  Round 19 (restore best).
// = Round 17 VERBATIM (381.5us total, stage2 216us): r13 phase-ordered Bs
//   pipeline + col-major pf5 [256][72] + P1-split + interior-store scatter.
// r18's L2-streamed bf REVERTED: per-phase loads were uncoalesced (stride
// 512B/lane -> 64 cache lines/wave/load) -> L2-latency-bound chain, 285us
// despite 85% occupancy. "L2-resident" != "free per-phase reads"; the Bs
// LDS pipeline amortizes exactly that latency. 7 structural alternatives
// (r7/8/9/11/14/15/18) all measured worse than this configuration.

#define NPTS 524288
#define NVOX 32768

typedef _Float16 f16;
typedef _Float16 f16x4 __attribute__((ext_vector_type(4)));
typedef _Float16 f16x8 __attribute__((ext_vector_type(8)));
typedef float f32x4 __attribute__((ext_vector_type(4)));

#define GLDS16(g, l)                                                          \
  __builtin_amdgcn_global_load_lds(                                           \
      (const __attribute__((address_space(1))) unsigned int*)(const void*)(g),\
      (__attribute__((address_space(3))) unsigned int*)(void*)(l), 16, 0, 0)

// ---------- idx normalization: auto-detect int32 vs int64 storage ----------
__global__ void k_fixidx(const int* __restrict__ raw, int* __restrict__ out) {
  bool is64 = true;
#pragma unroll
  for (int k = 0; k < 32; ++k)
    if (raw[2 * k + 1] != 0) is64 = false;   // int64 high words all 0 (vals < 32768)
  int stride = gridDim.x * blockDim.x;
  for (int i = blockIdx.x * blockDim.x + threadIdx.x; i < NPTS; i += stride)
    out[i] = is64 ? raw[2 * i] : raw[i];
}

// ---------- counting sort ----------
__global__ void k_hist(const int* __restrict__ idx, int* __restrict__ counts) {
  int stride = gridDim.x * blockDim.x;
  for (int i = blockIdx.x * blockDim.x + threadIdx.x; i < NPTS; i += stride)
    atomicAdd(&counts[idx[i]], 1);
}

__global__ void k_scan(const int* __restrict__ counts, int* __restrict__ offsets) {
  __shared__ int part[1024];
  __shared__ int sums[32];
  int t = threadIdx.x;
  int loc[32];
  int s = 0;
#pragma unroll
  for (int j = 0; j < 32; ++j) { loc[j] = counts[t * 32 + j]; s += loc[j]; }
  part[t] = s;
  __syncthreads();
  if (t < 32) {
    int run = 0;
    for (int j = 0; j < 32; ++j) { int tmp = part[t * 32 + j]; part[t * 32 + j] = run; run += tmp; }
    sums[t] = run;
  }
  __syncthreads();
  if (t == 0) {
    int run = 0;
    for (int i = 0; i < 32; ++i) { int tmp = sums[i]; sums[i] = run; run += tmp; }
  }
  __syncthreads();
  int b = part[t] + sums[t >> 5];
#pragma unroll
  for (int j = 0; j < 32; ++j) { offsets[t * 32 + j] = b; b += loc[j]; }
  if (t == 1023) offsets[NVOX] = b;
}

__global__ void k_scat(const int* __restrict__ idx, const int* __restrict__ offsets,
                       int* __restrict__ cursor, int* __restrict__ sp, int* __restrict__ sv) {
  int stride = gridDim.x * blockDim.x;
  for (int i = blockIdx.x * blockDim.x + threadIdx.x; i < NPTS; i += stride) {
    int v = idx[i];
    int pos = offsets[v] + atomicAdd(&cursor[v], 1);
    sp[pos] = i;
    sv[pos] = v;
  }
}

// ---------- standalone mlp1: pf1[s] = f16(relu(x[sp[s]] @ W1 + b1)) --------
__global__ void k_mlp1(const float* __restrict__ x, const int* __restrict__ sp,
                       const float* __restrict__ W1, const float* __restrict__ b1,
                       f16* __restrict__ pf1) {
  __shared__ float w[384];
  __shared__ float bb[64];
  int t = threadIdx.x;
  if (t < 384) w[t] = W1[t];
  if (t < 64) bb[t] = b1[t];
  __syncthreads();
  int stride = gridDim.x * blockDim.x;
  for (int s = blockIdx.x * blockDim.x + t; s < NPTS; s += stride) {
    int p = sp[s];
    const float* src = x + (size_t)p * 6;
    float x0 = src[0], x1 = src[1], x2 = src[2];
    float x3 = src[3], x4 = src[4], x5 = src[5];
    f16* dst = pf1 + (size_t)s * 64;
#pragma unroll
    for (int j0 = 0; j0 < 64; j0 += 8) {
      f16x8 o;
#pragma unroll
      for (int u = 0; u < 8; ++u) {
        int j = j0 + u;
        float a = bb[j];
        a += x0 * w[j];       a += x1 * w[64 + j];
        a += x2 * w[128 + j]; a += x3 * w[192 + j];
        a += x4 * w[256 + j]; a += x5 * w[320 + j];
        o[u] = (f16)fmaxf(a, 0.f);
      }
      *(f16x8*)(dst + j0) = o;
    }
  }
}

// ---------- weight transpose+cast: Wt[n][k] = (f16)W[k][n] ----------
__global__ void k_wcast(const float* __restrict__ W, f16* __restrict__ Wt, int K, int N) {
  int g = blockIdx.x * blockDim.x + threadIdx.x;
  if (g >= K * N) return;
  int k = g / N, n = g % N;
  Wt[n * K + k] = (f16)W[g];
}

__global__ void k_castf(const float* __restrict__ in, f16* __restrict__ out, int n) {
  int stride = gridDim.x * blockDim.x;
  for (int i = blockIdx.x * blockDim.x + threadIdx.x; i < n; i += stride)
    out[i] = (f16)in[i];
}

// ---------- generic f16 MFMA GEMM (validated round-4/6 core) ---------------
template <int K, int N, int MODEA, bool SCATTER, bool OUTF32, bool WRITEO, bool WTILE>
__global__ __launch_bounds__(256, 3) void k_gemm(
    const f16* __restrict__ A,
    const int* __restrict__ sv, const int* __restrict__ sp,
    const int* __restrict__ offs,
    const float* __restrict__ x, const float* __restrict__ W1, const float* __restrict__ b1,
    const f16* __restrict__ Bt,   // [N][K] pre-transposed
    const float* __restrict__ bias,
    f16* __restrict__ Of16, float* __restrict__ Of32, int row0) {
  constexpr int NT = N / 128;
  __shared__ __align__(16) char smem[32768];
  __shared__ float xs[MODEA == 2 ? 768 : 1];
  __shared__ int svp[MODEA == 2 ? 128 : 1];
  __shared__ int svx[SCATTER ? 128 : 1];
  f16* As = (f16*)smem;            // [128][64] per K-tile, 16B chunks XOR-swizzled
  f16* Bs = As + 128 * 64;

  int nwg = gridDim.x;             // all grids are multiples of 8
  int bid = blockIdx.x;
  int q = nwg >> 3;
  int swz = (bid & 7) * q + (bid >> 3);   // bijective XCD swizzle
  int tm = swz / NT, tn = swz % NT;
  int t = threadIdx.x;

  if (MODEA == 2) { if (t < 128) svp[t] = sp[row0 + tm * 128 + t]; }
  if (SCATTER) { if (t < 128) svx[t] = sv[row0 + tm * 128 + t]; }
  if (MODEA == 2) __syncthreads();

  int l = t & 63, w = t >> 6;
  int wm = w >> 1, wn = w & 1;
  int lrow = l & 15, lk = l >> 4;
  f32x4 acc[4][4] = {};

  constexpr int KT = K / 64;
#pragma unroll
  for (int kt = 0; kt < KT; ++kt) {
    int k0 = kt * 64;
#pragma unroll
    for (int i = 0; i < 4; ++i) {
      int n = i * 32 + (t >> 3);
      int clog = (t & 7) ^ (n & 7);
      GLDS16(Bt + (size_t)(tn * 128 + n) * K + k0 + clog * 8, Bs + i * 2048 + t * 8);
    }
    if constexpr (MODEA == 2) {
      for (int g = t; g < 768; g += 256) xs[g] = x[(size_t)svp[g / 6] * 6 + (g % 6)];
      __syncthreads();
      int j = t & 63;
      float wv[6];
#pragma unroll
      for (int i = 0; i < 6; ++i) wv[i] = W1[i * 64 + j];
      float bb = b1[j];
      int rb = (t >> 6) * 32;
#pragma unroll
      for (int rr = 0; rr < 32; ++rr) {
        int row = rb + rr;
        float a = bb;
#pragma unroll
        for (int i = 0; i < 6; ++i) a += xs[row * 6 + i] * wv[i];
        As[row * 64 + (((j >> 3) ^ (row & 7)) << 3) + (j & 7)] = (f16)fmaxf(a, 0.f);
      }
    } else {
#pragma unroll
      for (int i = 0; i < 4; ++i) {
        int row = i * 32 + (t >> 3);
        int clog = (t & 7) ^ (row & 7);
        GLDS16(A + (size_t)(tm * 128 + row) * K + k0 + clog * 8, As + i * 2048 + t * 8);
      }
    }
    __syncthreads();
#pragma unroll
    for (int ks = 0; ks < 2; ++ks) {
      f16x8 af[4], bf[4];
#pragma unroll
      for (int m = 0; m < 4; ++m) {
        int row = wm * 64 + m * 16 + lrow;
        int cp = (ks * 4 + lk) ^ (row & 7);
        af[m] = *(const f16x8*)(As + row * 64 + cp * 8);
      }
#pragma unroll
      for (int n = 0; n < 4; ++n) {
        int col = wn * 64 + n * 16 + lrow;
        int cp = (ks * 4 + lk) ^ (col & 7);
        bf[n] = *(const f16x8*)(Bs + col * 64 + cp * 8);
      }
#pragma unroll
      for (int m = 0; m < 4; ++m)
#pragma unroll
        for (int n = 0; n < 4; ++n)
          acc[m][n] = __builtin_amdgcn_mfma_f32_16x16x32_f16(af[m], bf[n], acc[m][n], 0, 0, 0);
    }
    __syncthreads();
  }

  if constexpr (WRITEO) {
#pragma unroll
    for (int m = 0; m < 4; ++m)
#pragma unroll
      for (int n = 0; n < 4; ++n)
#pragma unroll
        for (int j = 0; j < 4; ++j) {
          int row = wm * 64 + m * 16 + lk * 4 + j;       // C/D: row=(l>>4)*4+j
          int gc  = tn * 128 + wn * 64 + n * 16 + lrow;  // col=l&15
          float val = fmaxf(acc[m][n][j] + bias[gc], 0.f);
          if constexpr (OUTF32) Of32[(size_t)(tm * 128 + row) * N + gc] = val;
          else                  Of16[(size_t)(tm * 128 + row) * N + gc] = (f16)val;
        }
  }

  if constexpr (SCATTER) {
    f16* tile = (f16*)smem;   // [128][128] f16 (32KB, reuses As/Bs)
#pragma unroll
    for (int m = 0; m < 4; ++m)
#pragma unroll
      for (int n = 0; n < 4; ++n)
#pragma unroll
        for (int j = 0; j < 4; ++j) {
          int row = wm * 64 + m * 16 + lk * 4 + j;
          int col = wn * 64 + n * 16 + lrow;
          tile[row * 128 + col] =
              (f16)fmaxf(acc[m][n][j] + bias[tn * 128 + col], 0.f);
        }
    __syncthreads();
    if constexpr (WTILE) {
      // coalesced pf2 write from tile (values bit-identical to tile entries)
      f16* dst = Of16 + (size_t)(row0 + tm * 128) * 128;
#pragma unroll
      for (int i = 0; i < 8; ++i) {
        int g = i * 256 + t;
        *(f16x8*)(dst + g * 8) = *(const f16x8*)(tile + g * 8);
      }
    }
    int c = t & 127, h = t >> 7;    // 2 segments x 64 rows
    int r0l = h * 64;
    int gc = tn * 128 + c;
    int grow0 = row0 + tm * 128 + r0l;
    float run = 0.f;
    int curv = svx[r0l];
    for (int r = r0l; r < r0l + 64; ++r) {
      int v = svx[r];
      if (v != curv) {
        bool inter = (offs[curv] >= grow0) && (offs[curv + 1] <= grow0 + 64);
        if (inter) Of32[(size_t)curv * N + gc] = run;
        else atomicMax((int*)&Of32[(size_t)curv * N + gc], __float_as_int(run));
        curv = v; run = 0.f;
      }
      run = fmaxf(run, (float)tile[r * 128 + c]);
    }
    bool inter = (offs[curv] >= grow0) && (offs[curv + 1] <= grow0 + 64);
    if (inter) Of32[(size_t)curv * N + gc] = run;
    else atomicMax((int*)&Of32[(size_t)curv * N + gc], __float_as_int(run));
  }
}

// ---------- fused stage 2 (r13 core + col-major pf5; r17 validated) --------
// 64 rows/block, 512 thr / 8 waves; wave w owns cols [w*32, w*32+32).
// A staged full-K once (chunk-XOR [64][32ch]); B in K=32 chunks (16KB).
// Phase: bf-read -> bar -> stage-next(glds) -> af-read + 8 MFMA -> bar.
// pf4 row-major [64][264] padded; pf5 COLUMN-MAJOR [256][72] (b64 writes,
// b128 scan reads). PF region = 36864B, block LDS 53.5KB -> 3 blocks/CU.
__global__ __launch_bounds__(512, 2) void k_stage2(
    const f16* __restrict__ pf2, const f16* __restrict__ occ1,
    const int* __restrict__ sv, const int* __restrict__ offs,
    const f16* __restrict__ W3t, const float* __restrict__ b3,
    const f16* __restrict__ W4t, const float* __restrict__ b4,
    float* __restrict__ vox2f, int row0) {
  __shared__ __align__(16) f16 Bs[256 * 32];   // 16KB, one K=32 chunk of W
  __shared__ __align__(16) f16 PF[64 * 288];   // 36KB: A-full / pf4 / pf5(cm)
  __shared__ int svx[64];

  int nwg = gridDim.x;
  int bid = blockIdx.x;
  int q = nwg >> 3;
  int bm = (bid & 7) * q + (bid >> 3);   // bijective XCD swizzle
  int t = threadIdx.x;
  int l = t & 63, w = t >> 6;
  int lrow = l & 15, lk = l >> 4;

  if (t < 64) svx[t] = sv[row0 + bm * 64 + t];
  __syncthreads();

  // ---- stage A full-K [64 rows][32 chunks], chunk-XOR ----
  f16* Afull = PF;   // linear [64][256] with low-3-bit chunk XOR
#pragma unroll
  for (int ii = 0; ii < 4; ++ii) {
    int g = ii * 512 + t;
    int row = g >> 5, cs = g & 31;
    int cl = (cs & 24) | ((cs ^ row) & 7);   // inverse-swizzled source chunk
    const f16* src;
    if (cl < 16) src = occ1 + (size_t)svx[row] * 128 + cl * 8;
    else         src = pf2 + (size_t)(bm * 64 + row) * 128 + (cl - 16) * 8;
    GLDS16(src, Afull + g * 8);
  }
  // ---- stage W3 chunk 0: [256 n][32 k], cl = c ^ ((n>>1)&3) ----
#pragma unroll
  for (int ii = 0; ii < 2; ++ii) {
    int g = ii * 512 + t;
    int n = g >> 2, c = g & 3;
    int cl = c ^ ((n >> 1) & 3);
    GLDS16(W3t + (size_t)n * 256 + cl * 8, Bs + g * 8);
  }
  __syncthreads();   // A + B0 ready

  f32x4 acc[4][2] = {};

  // ---------------- mm3: 8 phases of K=32 ----------------------------------
#pragma unroll
  for (int p = 0; p < 8; ++p) {
    // (1) bf early-read from current Bs chunk (only these live across bar)
    f16x8 bf[2];
#pragma unroll
    for (int n = 0; n < 2; ++n) {
      int col = w * 32 + n * 16 + lrow;
      int cp = lk ^ ((col >> 1) & 3);
      bf[n] = *(const f16x8*)(Bs + col * 32 + cp * 8);
    }
    __syncthreads();   // all waves' Bs reads done -> safe to overwrite
    // (2) stage next chunk (glds in flight across MFMA below)
    {
      const f16* Wsrc = (p < 7) ? W3t : W4t;
      int kc = (p < 7) ? (p + 1) : 0;
#pragma unroll
      for (int ii = 0; ii < 2; ++ii) {
        int g = ii * 512 + t;
        int n = g >> 2, c = g & 3;
        int cl = c ^ ((n >> 1) & 3);
        GLDS16(Wsrc + (size_t)n * 256 + kc * 32 + cl * 8, Bs + g * 8);
      }
    }
    // (3) af reads + MFMA (overlaps glds flight)
    __builtin_amdgcn_s_setprio(1);
    f16x8 af[4];
#pragma unroll
    for (int m = 0; m < 4; ++m) {
      int row = m * 16 + lrow;
      int ab = p * 4 + lk;
      int slot = (ab & 24) | ((ab ^ row) & 7);
      af[m] = *(const f16x8*)(Afull + row * 256 + slot * 8);
    }
#pragma unroll
    for (int m = 0; m < 4; ++m)
#pragma unroll
      for (int n = 0; n < 2; ++n)
        acc[m][n] = __builtin_amdgcn_mfma_f32_16x16x32_f16(af[m], bf[n], acc[m][n], 0, 0, 0);
    __builtin_amdgcn_s_setprio(0);
    __syncthreads();   // drains glds -> next chunk ready
  }

  // ---- pf4 into PF region, row-major [64][264] (A dead after mm3) ---------
  f16* pf4 = PF;
#pragma unroll
  for (int m = 0; m < 4; ++m)
#pragma unroll
    for (int n = 0; n < 2; ++n)
#pragma unroll
      for (int j = 0; j < 4; ++j) {
        int row  = m * 16 + lk * 4 + j;      // C/D: row=(l>>4)*4+j, col=l&15
        int colg = w * 32 + n * 16 + lrow;
        pf4[row * 264 + colg] = (f16)fmaxf(acc[m][n][j] + b3[colg], 0.f);
      }
  __syncthreads();     // pf4 ready; W4 chunk 0 already staged+drained

#pragma unroll
  for (int m = 0; m < 4; ++m)
#pragma unroll
    for (int n = 0; n < 2; ++n)
      acc[m][n] = (f32x4){0.f, 0.f, 0.f, 0.f};

  // ---------------- mm4: 8 phases of K=32 ----------------------------------
#pragma unroll
  for (int p = 0; p < 8; ++p) {
    f16x8 bf[2];
#pragma unroll
    for (int n = 0; n < 2; ++n) {
      int col = w * 32 + n * 16 + lrow;
      int cp = lk ^ ((col >> 1) & 3);
      bf[n] = *(const f16x8*)(Bs + col * 32 + cp * 8);
    }
    __syncthreads();   // Bs reads done
    if (p < 7) {
#pragma unroll
      for (int ii = 0; ii < 2; ++ii) {
        int g = ii * 512 + t;
        int n = g >> 2, c = g & 3;
        int cl = c ^ ((n >> 1) & 3);
        GLDS16(W4t + (size_t)n * 256 + (p + 1) * 32 + cl * 8, Bs + g * 8);
      }
    }
    __builtin_amdgcn_s_setprio(1);
    f16x8 af[4];
#pragma unroll
    for (int m = 0; m < 4; ++m) {
      int row = m * 16 + lrow;
      int chunk = p * 4 + lk;                 // 0..31
      af[m] = *(const f16x8*)(pf4 + row * 264 + chunk * 8);
    }
#pragma unroll
    for (int m = 0; m < 4; ++m)
#pragma unroll
      for (int n = 0; n < 2; ++n)
        acc[m][n] = __builtin_amdgcn_mfma_f32_16x16x32_f16(af[m], bf[n], acc[m][n], 0, 0, 0);
    __builtin_amdgcn_s_setprio(0);
    __syncthreads();
  }

  // ---- pf5 COLUMN-MAJOR [256 cols][72] (pf4 fully consumed) ---------------
  // Each (m,n): 4 consecutive rows at one col -> single b64 store.
  f16* pf5 = PF;
#pragma unroll
  for (int m = 0; m < 4; ++m)
#pragma unroll
    for (int n = 0; n < 2; ++n) {
      int colg = w * 32 + n * 16 + lrow;
      int rowb = m * 16 + lk * 4;
      float bv = b4[colg];
      f16x4 v;
#pragma unroll
      for (int j = 0; j < 4; ++j) v[j] = (f16)fmaxf(acc[m][n][j] + bv, 0.f);
      *(f16x4*)(pf5 + colg * 72 + rowb) = v;
    }
  __syncthreads();

  // ---------------- scatter-max scan: vectorized col-major reads -----------
  {
    int c = t & 255, seg = t >> 8;   // 256 cols x 2 segs of 32 rows
    int r0l = seg * 32;
    int grow0 = row0 + bm * 64 + r0l;
    const f16* colp = pf5 + c * 72;
    float run = 0.f;
    int curv = svx[r0l];
#pragma unroll
    for (int rb = 0; rb < 32; rb += 8) {
      f16x8 vv = *(const f16x8*)(colp + r0l + rb);
#pragma unroll
      for (int u = 0; u < 8; ++u) {
        int r = r0l + rb + u;
        int v = svx[r];
        if (v != curv) {
          bool inter = (offs[curv] >= grow0) && (offs[curv + 1] <= grow0 + 32);
          if (inter) vox2f[(size_t)curv * 256 + c] = run;
          else atomicMax((int*)&vox2f[(size_t)curv * 256 + c], __float_as_int(run));
          curv = v; run = 0.f;
        }
        run = fmaxf(run, (float)vv[u]);
      }
    }
    bool inter = (offs[curv] >= grow0) && (offs[curv + 1] <= grow0 + 32);
    if (inter) vox2f[(size_t)curv * 256 + c] = run;
    else atomicMax((int*)&vox2f[(size_t)curv * 256 + c], __float_as_int(run));
  }
}

extern "C" void kernel_launch(void* const* d_in, const int* in_sizes, int n_in,
                              void* d_out, int out_size, void* d_ws, size_t ws_size,
                              hipStream_t stream) {
  const float* x   = (const float*)d_in[0];
  const int*  idxr = (const int*)d_in[1];
  const float* W1  = (const float*)d_in[3];
  const float* b1  = (const float*)d_in[4];
  const float* W2  = (const float*)d_in[5];
  const float* b2  = (const float*)d_in[6];
  const float* Wv1 = (const float*)d_in[7];
  const float* bv1 = (const float*)d_in[8];
  const float* W3  = (const float*)d_in[9];
  const float* b3  = (const float*)d_in[10];
  const float* W4  = (const float*)d_in[11];
  const float* b4  = (const float*)d_in[12];
  const float* Wv2 = (const float*)d_in[13];
  const float* bv2 = (const float*)d_in[14];
  float* out = (float*)d_out;

  char* ws = (char*)d_ws;
  size_t off = 0;
  auto alloc = [&](size_t bytes) {
    void* p = ws + off;
    off = (off + bytes + 255) & ~(size_t)255;
    return p;
  };
  int* idx     = (int*)alloc((size_t)NPTS * 4);
  int* counts  = (int*)alloc((size_t)NVOX * 4);
  int* cursor  = (int*)alloc((size_t)NVOX * 4);
  int* offs    = (int*)alloc((size_t)(NVOX + 1) * 4);
  int* sp      = (int*)alloc((size_t)NPTS * 4);
  int* sv      = (int*)alloc((size_t)NPTS * 4);
  f16* W2t     = (f16*)alloc(64 * 128 * 2);
  f16* Wv1t    = (f16*)alloc(128 * 128 * 2);
  f16* W3t     = (f16*)alloc(256 * 256 * 2);
  f16* W4t     = (f16*)alloc(256 * 256 * 2);
  f16* Wv2t    = (f16*)alloc(256 * 256 * 2);
  float* vox1f = (float*)alloc((size_t)NVOX * 128 * 4);
  f16* vox1h   = (f16*)alloc((size_t)NVOX * 128 * 2);
  f16* occ1    = (f16*)alloc((size_t)NVOX * 128 * 2);
  float* vox2f = (float*)alloc((size_t)NVOX * 256 * 4);

  // adaptive: pf2 full? + pf1 (split mlp1)?
  size_t rem = (ws_size > off) ? ws_size - off : 0;
  bool PF2FULL = rem >= (size_t)NPTS * 256 + 4096;
  int CH = 65536;
  f16* pf2   = (f16*)alloc(PF2FULL ? (size_t)NPTS * 256 : (size_t)CH * 256);
  f16* vox2h = pf2;   // overlay: pf2 dead once stage2 done
  size_t rem2 = (ws_size > off) ? ws_size - off : 0;
  bool MLP1SPLIT = PF2FULL && rem2 >= (size_t)NPTS * 128 + 4096;
  f16* pf1 = MLP1SPLIT ? (f16*)alloc((size_t)NPTS * 128) : nullptr;

  hipMemsetAsync(counts, 0, (size_t)NVOX * 4, stream);
  hipMemsetAsync(cursor, 0, (size_t)NVOX * 4, stream);
  hipMemsetAsync(vox1f, 0, (size_t)NVOX * 128 * 4, stream);
  hipMemsetAsync(vox2f, 0, (size_t)NVOX * 256 * 4, stream);

  k_fixidx<<<2048, 256, 0, stream>>>(idxr, idx);
  k_wcast<<<(64 * 128 + 255) / 256, 256, 0, stream>>>(W2, W2t, 64, 128);
  k_wcast<<<(128 * 128 + 255) / 256, 256, 0, stream>>>(Wv1, Wv1t, 128, 128);
  k_wcast<<<(256 * 256 + 255) / 256, 256, 0, stream>>>(W3, W3t, 256, 256);
  k_wcast<<<(256 * 256 + 255) / 256, 256, 0, stream>>>(W4, W4t, 256, 256);
  k_wcast<<<(256 * 256 + 255) / 256, 256, 0, stream>>>(Wv2, Wv2t, 256, 256);
  k_hist<<<2048, 256, 0, stream>>>(idx, counts);
  k_scan<<<1, 1024, 0, stream>>>(counts, offs);
  k_scat<<<2048, 256, 0, stream>>>(idx, offs, cursor, sp, sv);

  // P1: mlp1 (split or fused) + mm2 + segment-max -> vox1f (+ pf2)
  if (MLP1SPLIT) {
    k_mlp1<<<2048, 256, 0, stream>>>(x, sp, W1, b1, pf1);
    k_gemm<64, 128, 0, true, false, false, true><<<NPTS / 128, 256, 0, stream>>>(
        pf1, sv, sp, offs, x, W1, b1, W2t, b2, pf2, vox1f, 0);
  } else if (PF2FULL) {
    k_gemm<64, 128, 2, true, false, false, true><<<NPTS / 128, 256, 0, stream>>>(
        nullptr, sv, sp, offs, x, W1, b1, W2t, b2, pf2, vox1f, 0);
  } else {
    k_gemm<64, 128, 2, true, false, false, false><<<NPTS / 128, 256, 0, stream>>>(
        nullptr, sv, sp, offs, x, W1, b1, W2t, b2, nullptr, vox1f, 0);
  }
  k_castf<<<2048, 256, 0, stream>>>(vox1f, vox1h, NVOX * 128);
  // mmv1: occ1 = relu(vox1 @ Wv1 + bv1)
  k_gemm<128, 128, 0, false, false, true, false><<<NVOX / 128, 256, 0, stream>>>(
      vox1h, nullptr, nullptr, nullptr, nullptr, nullptr, nullptr,
      Wv1t, bv1, occ1, nullptr, 0);

  // stage 2: fused mm3+mm4+scatter, 3 blocks/CU
  if (PF2FULL) {
    k_stage2<<<NPTS / 64, 512, 0, stream>>>(
        pf2, occ1, sv, offs, W3t, b3, W4t, b4, vox2f, 0);
  } else {
    for (int c = 0; c < NPTS / CH; ++c) {
      int row0 = c * CH;
      k_gemm<64, 128, 2, false, false, true, false><<<CH / 128, 256, 0, stream>>>(
          nullptr, nullptr, sp, nullptr, x, W1, b1, W2t, b2, pf2, nullptr, row0);
      k_stage2<<<CH / 64, 512, 0, stream>>>(
          pf2, occ1, sv, offs, W3t, b3, W4t, b4, vox2f, row0);
    }
  }

  k_castf<<<2048, 256, 0, stream>>>(vox2f, vox2h, NVOX * 256);
  // mmv2: out = relu(vox2 @ Wv2 + bv2), f32 output via MFMA
  k_gemm<256, 256, 0, false, true, true, false><<<(NVOX / 128) * 2, 256, 0, stream>>>(
      vox2h, nullptr, nullptr, nullptr, nullptr, nullptr, nullptr,
      Wv2t, bv2, nullptr, out, 0);
}